// Round 5
// baseline (1071.320 us; speedup 1.0000x reference)
//
#include <hip/hip_runtime.h>

// SparseGlobalPool: segment-mean of features [N, C=128] over batch_ids in [0, B=32).
// out[b][c] = mean of features[i][c] where batch_ids[i]==b, 0 if empty.
//
// ws layout: float sums[B*C] ; unsigned counts[B]   (4128 dwords = 16.5 KB)
//
// Round-1/2 lesson: LDS float atomics (ds_add_f32, safe OR unsafe) serialize on
// the LDS atomic pipe under 32-segment contention -> 1285us @ 0.8% VALUBusy.
// Round-4 lesson: __launch_bounds__(512) without the occupancy arg made the
// allocator target 8 waves/EU (<=64 VGPR) and SPILL the 32 float2 register
// accumulators to scratch (VGPR_Count=56, WRITE_SIZE=136MB of spill traffic).
// Fix: __launch_bounds__(512, 2) -> 256-VGPR budget, accumulators stay in VGPRs.

constexpr int CH = 128;     // channels
constexpr int BATCH = 32;   // segments

#define SGP_FOREACH(X) \
    X(0) X(1) X(2) X(3) X(4) X(5) X(6) X(7) \
    X(8) X(9) X(10) X(11) X(12) X(13) X(14) X(15) \
    X(16) X(17) X(18) X(19) X(20) X(21) X(22) X(23) \
    X(24) X(25) X(26) X(27) X(28) X(29) X(30) X(31)

#define SGP_FOREACH2(X, A) \
    X(0,A) X(1,A) X(2,A) X(3,A) X(4,A) X(5,A) X(6,A) X(7,A) \
    X(8,A) X(9,A) X(10,A) X(11,A) X(12,A) X(13,A) X(14,A) X(15,A) \
    X(16,A) X(17,A) X(18,A) X(19,A) X(20,A) X(21,A) X(22,A) X(23,A) \
    X(24,A) X(25,A) X(26,A) X(27,A) X(28,A) X(29,A) X(30,A) X(31,A)

__global__ __launch_bounds__(512) void sgp_zero(float* ws, int n) {
    int i = blockIdx.x * blockDim.x + threadIdx.x;
    if (i < n) ws[i] = 0.0f;   // bit-pattern 0 also zeroes the uint counts
}

__global__ __launch_bounds__(512, 2) void sgp_accum(const float2* __restrict__ feat2,
                                                    const int* __restrict__ bid,
                                                    float* __restrict__ gsum,
                                                    unsigned int* __restrict__ gcnt,
                                                    int N) {
    const int lane = threadIdx.x & 63;
    // wave-uniform wave id (SGPR) -> row indices are scalar -> bid loads scalar
    const int w  = __builtin_amdgcn_readfirstlane(
                       (int)(blockIdx.x * (blockDim.x >> 6) + (threadIdx.x >> 6)));
    const int NW = gridDim.x * (blockDim.x >> 6);   // total waves

    // 32 named register accumulators (float2 = this lane's 2 channels) + counts.
    // Counts are uniform -> SGPRs; float2 accs are VGPRs (64 total).
#define SGP_DECL(k) float2 a##k = {0.0f, 0.0f}; unsigned c##k = 0u;
    SGP_FOREACH(SGP_DECL)
#undef SGP_DECL

    // uniform (scalar) 32-way dispatch: 2 v_add_f32 + 1 s_add per row
#define SGP_CASE(k, V) case k: a##k.x += (V).x; a##k.y += (V).y; c##k += 1u; break;
#define SGP_ACC(B, V) switch (B) { SGP_FOREACH2(SGP_CASE, V) default: break; }

    int base = w * 4;
    const int stride = NW * 4;
    for (; base + 4 <= N; base += stride) {
        // scalar batch-id loads (wave-uniform)
        const int b0 = __builtin_amdgcn_readfirstlane(bid[base + 0]);
        const int b1 = __builtin_amdgcn_readfirstlane(bid[base + 1]);
        const int b2 = __builtin_amdgcn_readfirstlane(bid[base + 2]);
        const int b3 = __builtin_amdgcn_readfirstlane(bid[base + 3]);
        // 4 rows in flight: 4 x dwordx2, 512B/wave each, 2KB contiguous total
        const float2 v0 = feat2[(size_t)(base + 0) * 64 + lane];
        const float2 v1 = feat2[(size_t)(base + 1) * 64 + lane];
        const float2 v2 = feat2[(size_t)(base + 2) * 64 + lane];
        const float2 v3 = feat2[(size_t)(base + 3) * 64 + lane];

        SGP_ACC(b0, v0)
        SGP_ACC(b1, v1)
        SGP_ACC(b2, v2)
        SGP_ACC(b3, v3)
    }
    // tail rows (only the few waves whose last chunk straddles N)
    if (base < N) {
        for (int r = base; r < N; ++r) {
            const int b = __builtin_amdgcn_readfirstlane(bid[r]);
            const float2 v = feat2[(size_t)r * 64 + lane];
            SGP_ACC(b, v)
        }
    }

    // flush: per wave, 64 global fp atomics (hardware global_atomic_add_f32)
    // + 32 count atomics from lane 0. ~4096 waves -> <=4096 RMWs per address.
    const int ch2 = lane << 1;
#define SGP_FLUSH(k) \
    unsafeAtomicAdd(&gsum[k * CH + ch2], a##k.x); \
    unsafeAtomicAdd(&gsum[k * CH + ch2 + 1], a##k.y); \
    if (lane == 0) atomicAdd(&gcnt[k], c##k);
    SGP_FOREACH(SGP_FLUSH)
#undef SGP_FLUSH
}

__global__ __launch_bounds__(256) void sgp_final(const float* __restrict__ gsum,
                                                 const unsigned int* __restrict__ gcnt,
                                                 float* __restrict__ out) {
    int idx = blockIdx.x * blockDim.x + threadIdx.x;
    if (idx < BATCH * CH) {
        const unsigned int c = gcnt[idx >> 7];
        out[idx] = (c > 0u) ? gsum[idx] / (float)c : 0.0f;
    }
}

extern "C" void kernel_launch(void* const* d_in, const int* in_sizes, int n_in,
                              void* d_out, int out_size, void* d_ws, size_t ws_size,
                              hipStream_t stream) {
    const float2* feat2 = (const float2*)d_in[0];
    const int* bid      = (const int*)d_in[1];
    const int N = in_sizes[1];

    float* gsum        = (float*)d_ws;
    unsigned int* gcnt = (unsigned int*)((char*)d_ws + BATCH * CH * sizeof(float));

    const int ws_dwords = BATCH * CH + BATCH;  // 4128
    sgp_zero<<<(ws_dwords + 511) / 512, 512, 0, stream>>>((float*)d_ws, ws_dwords);

    // 512 blocks x 512 thr = 4096 waves; each wave owns whole rows (float2/lane),
    // 4 rows in flight -> at 16 waves/CU that's ~32KB in-flight per CU.
    sgp_accum<<<512, 512, 0, stream>>>(feat2, bid, gsum, gcnt, N);

    sgp_final<<<(BATCH * CH + 255) / 256, 256, 0, stream>>>(gsum, gcnt, (float*)d_out);
}

// Round 6
// 219.882 us; speedup vs baseline: 4.8722x; 4.8722x over previous
//
#include <hip/hip_runtime.h>

// SparseGlobalPool: segment-mean of features [N, C=128] over batch_ids in [0, B=32).
// out[b][c] = mean of features[i][c] where batch_ids[i]==b, 0 if empty.
//
// ws layout: float sums[B*C] ; unsigned counts[B]   (4128 dwords = 16.5 KB)
//
// Round-1/2: LDS float ATOMICS serialize on the LDS atomic pipe under
//   32-segment cross-wave contention (1285us @ 0.8% VALUBusy). Banned.
// Round-4/5: 32 named float2 register accumulators behind a 32-case switch get
//   lowered to a scratch ARRAY (rule #20) -> VGPR=56 < 64 needed, 136MB spill
//   traffic, ~1100us, independent of __launch_bounds__. Banned.
// This version: per-wave PRIVATE LDS accumulator (plain ds_read/add/ds_write,
//   no atomics, no contention, no indexed registers). Counts via the lane==b
//   register trick (no switch). Depth-1 prefetch for HBM overlap.

constexpr int CH = 128;       // channels
constexpr int BATCH = 32;     // segments
constexpr int WPB = 4;        // waves per block (256 threads)
constexpr int RPC = 4;        // rows per chunk

__global__ __launch_bounds__(512) void sgp_zero(float* ws, int n) {
    int i = blockIdx.x * blockDim.x + threadIdx.x;
    if (i < n) ws[i] = 0.0f;   // bit-pattern 0 also zeroes the uint counts
}

__global__ __launch_bounds__(256) void sgp_accum(const float2* __restrict__ feat2,
                                                 const int* __restrict__ bid,
                                                 float* __restrict__ gsum,
                                                 unsigned int* __restrict__ gcnt,
                                                 int N) {
    // Per-wave private accumulator: acc[wave][seg][lane] (float2 = 2 channels).
    // 4 waves x 32 segs x 64 lanes x 8B = 65536 B exactly.
    __shared__ float2 acc[WPB][BATCH][64];

    const int tid  = threadIdx.x;
    const int lane = tid & 63;
    const int wib  = tid >> 6;    // wave index in block

    for (int i = tid; i < WPB * BATCH * 64; i += 256)
        (&acc[0][0][0])[i] = make_float2(0.0f, 0.0f);
    __syncthreads();

    const int w  = __builtin_amdgcn_readfirstlane((int)(blockIdx.x * WPB + wib));
    const int NW = gridDim.x * WPB;       // total waves
    const int F  = N >> 2;                // full 4-row chunks

    unsigned mycnt = 0u;                  // lane b counts rows with bid==b

    float2 v[RPC];
    int    b4[RPC];
    int c = w;
    if (c < F) {
        #pragma unroll
        for (int j = 0; j < RPC; ++j) {
            v[j]  = feat2[(size_t)(4 * c + j) * 64 + lane];
            b4[j] = bid[4 * c + j];
        }
    }
    while (c < F) {
        const int cn = c + NW;
        float2 nv[RPC];
        int    nb[RPC];
        if (cn < F) {
            // prefetch next chunk before touching LDS (hides HBM latency)
            #pragma unroll
            for (int j = 0; j < RPC; ++j) {
                nv[j] = feat2[(size_t)(4 * cn + j) * 64 + lane];
                nb[j] = bid[4 * cn + j];
            }
        }
        // process current chunk: plain LDS RMW, strictly in program order so
        // same-segment rows within the chunk accumulate correctly (DS ops from
        // one wave execute in order; compiler can't reorder across may-alias).
        #pragma unroll
        for (int j = 0; j < RPC; ++j) {
            const int b = __builtin_amdgcn_readfirstlane(b4[j]);
            float2 o = acc[wib][b][lane];
            o.x += v[j].x;
            o.y += v[j].y;
            acc[wib][b][lane] = o;
            mycnt += (lane == b) ? 1u : 0u;
        }
        if (cn < F) {
            #pragma unroll
            for (int j = 0; j < RPC; ++j) { v[j] = nv[j]; b4[j] = nb[j]; }
        }
        c = cn;
    }
    // tail rows (N % 4), handled by wave 0 only
    if (w == 0) {
        for (int r = (N & ~3); r < N; ++r) {
            const int b = __builtin_amdgcn_readfirstlane(bid[r]);
            const float2 t = feat2[(size_t)r * 64 + lane];
            float2 o = acc[wib][b][lane];
            o.x += t.x;
            o.y += t.y;
            acc[wib][b][lane] = o;
            mycnt += (lane == b) ? 1u : 0u;
        }
    }

    // counts: one wave-op per wave, 32 distinct addresses (no same-addr within op)
    if (lane < BATCH) atomicAdd(&gcnt[lane], mycnt);

    __syncthreads();

    // block-reduce the 4 wave-regions and flush: 2048 float2 entries, 256 thr
    for (int e = tid; e < BATCH * 64; e += 256) {
        const int seg = e >> 6;
        const int ln  = e & 63;
        float2 s  = acc[0][seg][ln];
        float2 t1 = acc[1][seg][ln];
        float2 t2 = acc[2][seg][ln];
        float2 t3 = acc[3][seg][ln];
        s.x += t1.x + t2.x + t3.x;
        s.y += t1.y + t2.y + t3.y;
        unsafeAtomicAdd(&gsum[seg * CH + ln * 2],     s.x);
        unsafeAtomicAdd(&gsum[seg * CH + ln * 2 + 1], s.y);
    }
}

__global__ __launch_bounds__(256) void sgp_final(const float* __restrict__ gsum,
                                                 const unsigned int* __restrict__ gcnt,
                                                 float* __restrict__ out) {
    int idx = blockIdx.x * blockDim.x + threadIdx.x;
    if (idx < BATCH * CH) {
        const unsigned int c = gcnt[idx >> 7];
        out[idx] = (c > 0u) ? gsum[idx] / (float)c : 0.0f;
    }
}

extern "C" void kernel_launch(void* const* d_in, const int* in_sizes, int n_in,
                              void* d_out, int out_size, void* d_ws, size_t ws_size,
                              hipStream_t stream) {
    const float2* feat2 = (const float2*)d_in[0];
    const int* bid      = (const int*)d_in[1];
    const int N = in_sizes[1];

    float* gsum        = (float*)d_ws;
    unsigned int* gcnt = (unsigned int*)((char*)d_ws + BATCH * CH * sizeof(float));

    const int ws_dwords = BATCH * CH + BATCH;  // 4128
    sgp_zero<<<(ws_dwords + 511) / 512, 512, 0, stream>>>((float*)d_ws, ws_dwords);

    // 512 blocks x 256 thr = 2048 waves; 64KB LDS/block -> 2 blocks/CU resident
    // (8 waves/CU), depth-1 prefetch keeps ~16KB/CU of HBM loads in flight.
    sgp_accum<<<512, 256, 0, stream>>>(feat2, bid, gsum, gcnt, N);

    sgp_final<<<(BATCH * CH + 255) / 256, 256, 0, stream>>>(gsum, gcnt, (float*)d_out);
}